// Round 11
// baseline (124.735 us; speedup 1.0000x reference)
//
#include <hip/hip_runtime.h>

// SlidingKernelAttention: unfold(k=4,s=1) -> per-(b,c,patch-offset) attention
// over seq=256 tokens of dim=16 -> overlap-add fold.
// B=2, C=64, H=W=67, Ho=Wo=64, N = B*C*16 = 2048 independent sequences.
//
// R11: SINGLE FUSED KERNEL. Evidence: R7/R8/R9 post-fill work clusters at
// 45.5/43.5/41.7us ~= the 42us HBM drain of the harness's 268MB d_ws poison
// fill (268MB / 6.3TB/s); targeted compute changes move totals ~2us only =>
// pass1 was latency-bound against drain-congested HBM (x re-read 16x from a
// fill-dirty L2). Fix: one block per (bc, row-half) keeps the 35KB x-plane
// L1-resident, computes all 16 sequences serially (2 concurrent x 8 waves),
// folds in-LDS (f32 facc + ds_add atomics), writes out directly.
// HBM traffic: ~4.6MB read + 2.3MB write (was ~37MB read + 19MB write).
// No d_ws use. Row ownership: qh0 -> out rows 0..34 (q-tiles 0..8),
// qh1 -> rows 35..66 (q-tiles 8..15); tile 8 duplicated; per-lane guards.
//
// MFMA layout identity (R5-R10): 16x16 MFMA C/D layout == A-operand layout
// == B-operand layout, so projection MFMA results ARE attention operands:
//   K^T = Wk.X^T    -> A-frag of K      (for S^T = K.Q^T)
//   V   = X.Wv^T    -> A-frag of V^T    (for O^T = V^T.P^T)
//   Q^T = s.Wq.X^T  -> B-frag of Q^T
//   P^T = exp2(S^T) -> B-frag of P^T    (in-register)
// Register arrays statically indexed (R4 lesson; LDS dynamic indexing is
// fine). f16 vectors via v_cvt_pkrtz + bit_cast / shufflevector (R8 lesson).

#define BATCH 2
#define CHAN 64
#define HWDIM 67
#define DIM 16
#define ATT_SCALE 0.70710678118654752f             // (DIM/HEADS)^-0.5
#define LOG2E 1.44269504088896340736f

typedef _Float16 half4 __attribute__((ext_vector_type(4)));
typedef _Float16 half8 __attribute__((ext_vector_type(8)));
typedef float float4v __attribute__((ext_vector_type(4)));
typedef __fp16 fp16x2 __attribute__((ext_vector_type(2)));
typedef unsigned int uint2v __attribute__((ext_vector_type(2)));

static __device__ __forceinline__ half4 mk_half4(float a, float b, float c, float d) {
    fp16x2 lo = __builtin_amdgcn_cvt_pkrtz(a, b);
    fp16x2 hi = __builtin_amdgcn_cvt_pkrtz(c, d);
    uint2v u;
    u[0] = __builtin_bit_cast(unsigned int, lo);
    u[1] = __builtin_bit_cast(unsigned int, hi);
    return __builtin_bit_cast(half4, u);
}

static __device__ __forceinline__ half4 pack4(float4v c) {
    return mk_half4(c[0], c[1], c[2], c[3]);
}

__global__ __launch_bounds__(1024, 4) void ska_fused(
    const float* __restrict__ x,      // [B, C, 67, 67]
    const float* __restrict__ w,      // [48, 16]
    float* __restrict__ out)          // [B, C, 67, 67]
{
    // per 2-seq group: X fragments + K/V fragments for both sequences
    __shared__ __align__(16) _Float16 bufX [2][16][64][4];   // 16 KB
    __shared__ __align__(16) _Float16 bufKV[2][16][64][8];   // 32 KB
    __shared__ float facc[35 * HWDIM];                       // fold acc, 9.4 KB

    const int tid = threadIdx.x;
    const int blk = blockIdx.x;
    const int bc  = blk >> 1;
    const int qh  = blk & 1;
    const int rowbase = qh ? 35 : 0;
    const int nrows   = qh ? 32 : 35;
    const int nflat   = nrows * HWDIM;

    // zero the fold accumulator (first __syncthreads below makes it visible)
    for (int idx = tid; idx < nflat; idx += 1024) facc[idx] = 0.f;

    const int W    = tid >> 6;        // wave 0..15
    const int lane = tid & 63;
    const int sid  = W >> 3;          // which of the 2 concurrent sequences
    const int wv   = W & 7;           // wave within sequence group
    const int o    = lane & 15;
    const int g    = lane >> 4;

    // weight fragments from global (3 KB, L1-broadcast)
    const float4 wq4 = *(const float4*)(w + ( 0 + o) * DIM + 4 * g);
    const float4 wk4 = *(const float4*)(w + (16 + o) * DIM + 4 * g);
    const float4 wv4 = *(const float4*)(w + (32 + o) * DIM + 4 * g);
    const half4 wqf = mk_half4(wq4.x * (ATT_SCALE * LOG2E), wq4.y * (ATT_SCALE * LOG2E),
                               wq4.z * (ATT_SCALE * LOG2E), wq4.w * (ATT_SCALE * LOG2E));
    const half4 wkf = mk_half4(wk4.x, wk4.y, wk4.z, wk4.w);
    const half4 wvf = mk_half4(wv4.x, wv4.y, wv4.z, wv4.w);

    const float4v zf = (float4v){0.f, 0.f, 0.f, 0.f};

    // attention q-tile assignment: qh0 -> tiles 0..8 (wave0 takes 0 and 8),
    // qh1 -> tiles 8..15 (one each)
    const int  t0  = qh ? (8 + wv) : wv;
    const bool do2 = (qh == 0) && (wv == 0);

    // staging mapping: 2 threads per token (8 features each)
    const int stok = (tid >> 1) & 255;
    const int sdh2 = tid & 1;

    for (int u = 0; u < 8; ++u) {
        const int p = 2 * u + sid;        // this half-block's sequence
        const int i = p >> 2;
        const int j = p & 3;

        // ---- stage X fragments (f16) straight from global (L1-hot plane)
        {
            const int kt = stok >> 4, kk = stok & 15;
            const float* src = x + ((size_t)bc * HWDIM + (stok >> 2) + i) * HWDIM
                                 + (stok & 3) * DIM + 8 * sdh2 + j;
            const half4 h0 = mk_half4(src[0], src[1], src[2], src[3]);
            const half4 h1 = mk_half4(src[4], src[5], src[6], src[7]);
            *(half4*)&bufX[sid][kt][kk + 16 * (2 * sdh2)][0]     = h0;
            *(half4*)&bufX[sid][kt][kk + 16 * (2 * sdh2 + 1)][0] = h1;
        }
        __syncthreads();   // bufX ready (also covers facc zero on u==0)

        // ---- projection: K/V for tiles 2wv, 2wv+1; Q for this wave's tiles
        {
            const int tt0 = 2 * wv, tt1 = 2 * wv + 1;
            const half4 xf0 = *(const half4*)&bufX[sid][tt0][lane][0];
            const half4 xf1 = *(const half4*)&bufX[sid][tt1][lane][0];
            const half4 kf0 = pack4(__builtin_amdgcn_mfma_f32_16x16x16f16(wkf, xf0, zf, 0, 0, 0));
            const half4 vf0 = pack4(__builtin_amdgcn_mfma_f32_16x16x16f16(xf0, wvf, zf, 0, 0, 0));
            const half4 kf1 = pack4(__builtin_amdgcn_mfma_f32_16x16x16f16(wkf, xf1, zf, 0, 0, 0));
            const half4 vf1 = pack4(__builtin_amdgcn_mfma_f32_16x16x16f16(xf1, wvf, zf, 0, 0, 0));
            *(half8*)&bufKV[sid][tt0][lane][0] = __builtin_shufflevector(kf0, vf0, 0, 1, 2, 3, 4, 5, 6, 7);
            *(half8*)&bufKV[sid][tt1][lane][0] = __builtin_shufflevector(kf1, vf1, 0, 1, 2, 3, 4, 5, 6, 7);
        }
        const half4 xq0 = *(const half4*)&bufX[sid][t0][lane][0];
        half4 qfr0 = pack4(__builtin_amdgcn_mfma_f32_16x16x16f16(wqf, xq0, zf, 0, 0, 0));
        half4 qfr1 = qfr0;
        if (do2) {
            const half4 xq1 = *(const half4*)&bufX[sid][8][lane][0];
            qfr1 = pack4(__builtin_amdgcn_mfma_f32_16x16x16f16(wqf, xq1, zf, 0, 0, 0));
        }
        __syncthreads();   // bufKV ready

        // ---- attention over 16 k-tiles
        float4v oa0 = zf, oa1 = zf;
        float lp0 = 0.f, lp1 = 0.f;
#pragma unroll
        for (int t = 0; t < 16; ++t) {
            const half8 kv = *(const half8*)&bufKV[sid][t][lane][0];
            const half4 kf = __builtin_shufflevector(kv, kv, 0, 1, 2, 3);
            const half4 vf = __builtin_shufflevector(kv, kv, 4, 5, 6, 7);
            {
                float4v sfr = __builtin_amdgcn_mfma_f32_16x16x16f16(kf, qfr0, zf, 0, 0, 0);
                const float p0 = __builtin_amdgcn_exp2f(sfr[0]);
                const float p1 = __builtin_amdgcn_exp2f(sfr[1]);
                const float p2 = __builtin_amdgcn_exp2f(sfr[2]);
                const float p3 = __builtin_amdgcn_exp2f(sfr[3]);
                lp0 += (p0 + p1) + (p2 + p3);
                oa0 = __builtin_amdgcn_mfma_f32_16x16x16f16(vf, mk_half4(p0, p1, p2, p3), oa0, 0, 0, 0);
            }
            if (do2) {
                float4v sfr = __builtin_amdgcn_mfma_f32_16x16x16f16(kf, qfr1, zf, 0, 0, 0);
                const float p0 = __builtin_amdgcn_exp2f(sfr[0]);
                const float p1 = __builtin_amdgcn_exp2f(sfr[1]);
                const float p2 = __builtin_amdgcn_exp2f(sfr[2]);
                const float p3 = __builtin_amdgcn_exp2f(sfr[3]);
                lp1 += (p0 + p1) + (p2 + p3);
                oa1 = __builtin_amdgcn_mfma_f32_16x16x16f16(vf, mk_half4(p0, p1, p2, p3), oa1, 0, 0, 0);
            }
        }

        // ---- normalize + fold into LDS accumulator (ds atomic f32 add)
        {
            float lj = lp0;
            lj += __shfl_xor(lj, 16, 64);
            lj += __shfl_xor(lj, 32, 64);
            const float rl = 1.f / lj;
            const int rho = 4 * t0 + ((lane & 15) >> 2);    // plane row
            const int h   = rho + i;                        // out row
            const int fr  = h - rowbase;
            if (fr >= 0 && fr < nrows) {
                const int col = (lane & 3) * 16 + 4 * g + j;
                float* fb = &facc[fr * HWDIM + col];
                atomicAdd(fb + 0, oa0[0] * rl);
                atomicAdd(fb + 1, oa0[1] * rl);
                atomicAdd(fb + 2, oa0[2] * rl);
                atomicAdd(fb + 3, oa0[3] * rl);
            }
        }
        if (do2) {
            float lj = lp1;
            lj += __shfl_xor(lj, 16, 64);
            lj += __shfl_xor(lj, 32, 64);
            const float rl = 1.f / lj;
            const int rho = 4 * 8 + ((lane & 15) >> 2);
            const int h   = rho + i;
            const int fr  = h - rowbase;
            if (fr >= 0 && fr < nrows) {
                const int col = (lane & 3) * 16 + 4 * g + j;
                float* fb = &facc[fr * HWDIM + col];
                atomicAdd(fb + 0, oa1[0] * rl);
                atomicAdd(fb + 1, oa1[1] * rl);
                atomicAdd(fb + 2, oa1[2] * rl);
                atomicAdd(fb + 3, oa1[3] * rl);
            }
        }
        __syncthreads();   // folds done before next group's staging overwrite
    }

    // ---- write owned output rows (coalesced f32)
    for (int idx = tid; idx < nflat; idx += 1024) {
        const int hr = idx / HWDIM;
        const int wc = idx - hr * HWDIM;
        out[((size_t)bc * HWDIM + rowbase + hr) * HWDIM + wc] = facc[idx];
    }
}

extern "C" void kernel_launch(void* const* d_in, const int* in_sizes, int n_in,
                              void* d_out, int out_size, void* d_ws, size_t ws_size,
                              hipStream_t stream) {
    const float* x = (const float*)d_in[0];
    const float* w = (const float*)d_in[1];
    float* out = (float*)d_out;
    (void)d_ws; (void)ws_size; (void)in_sizes; (void)n_in; (void)out_size;

    ska_fused<<<BATCH * CHAN * 2, 1024, 0, stream>>>(x, w, out);
}